// Round 7
// baseline (837.618 us; speedup 1.0000x reference)
//
#include <hip/hip_runtime.h>
#include <stdint.h>

#define T_TOK   16384
#define D_INK   2048
#define D_OUTN  8192
#define G_NUM   8

#define BM 256
#define BN 256
#define BK 64
#define NKT (D_INK / BK)        // 32 K-tiles (even -> clean 2-tile supersteps)
#define MT_TILES (T_TOK / BM)   // 64
#define NT_TILES (D_OUTN / BN)  // 32

typedef __attribute__((ext_vector_type(8))) short bf16x8;
typedef __attribute__((ext_vector_type(4))) float f32x4;
typedef __attribute__((ext_vector_type(16))) float f32x16;

#define BARRIER() do { asm volatile("" ::: "memory"); __builtin_amdgcn_s_barrier(); asm volatile("" ::: "memory"); } while (0)
#define VMCNT(n)  asm volatile("s_waitcnt vmcnt(" #n ")" ::: "memory")

// ---------- fp32 -> bf16 (RNE) conversion, vectorized ----------
__device__ __forceinline__ unsigned int f2bf(float f) {
    union { float f; unsigned int u; } v; v.f = f;
    unsigned int u = v.u;
    unsigned int r = u + 0x7FFFu + ((u >> 16) & 1u);
    return r >> 16;
}

__global__ __launch_bounds__(256) void cvt_f32_bf16(const float* __restrict__ src,
                                                    unsigned short* __restrict__ dst,
                                                    long long n8) {
    long long i = (long long)blockIdx.x * blockDim.x + threadIdx.x;
    long long stride = (long long)gridDim.x * blockDim.x;
    const float4* s4 = reinterpret_cast<const float4*>(src);
    for (; i < n8; i += stride) {
        float4 x = s4[i * 2];
        float4 y = s4[i * 2 + 1];
        uint4 o;
        o.x = f2bf(x.x) | (f2bf(x.y) << 16);
        o.y = f2bf(x.z) | (f2bf(x.w) << 16);
        o.z = f2bf(y.x) | (f2bf(y.y) << 16);
        o.w = f2bf(y.z) | (f2bf(y.w) << 16);
        *reinterpret_cast<uint4*>(dst + i * 8) = o;
    }
}

// ---------- async global->LDS, 16B per lane ----------
__device__ __forceinline__ void gload_lds16(const unsigned short* g, void* l) {
    __builtin_amdgcn_global_load_lds(
        (const __attribute__((address_space(1))) void*)g,
        (__attribute__((address_space(3))) void*)l,
        16, 0, 0);
}

// ---------- 256x256 8-phase grouped GEMM: C[t,o] = sum_k A[t,k] * W[g][o,k] ----------
// LDS per operand tile [256 rows][64 k]: 32 subtiles of 16x32 bf16 (1024 B),
// st_16x32 swizzle (measured R2-R6: SQ_LDS_BANK_CONFLICT == 0); gload_lds writes
// linearly, swizzle inverse folded into per-lane GLOBAL address (rule #21).
// Schedule: R4's (best measured): 2-K-tile superstep, 8 phases, in-phase fragment
// reads, one half-tile stage per phase, vmcnt(4) twice per superstep, never 0.
// THIS ROUND: inner MFMA swapped 16x16x32 -> 32x32x16 (m119: 32x32 pipe is ~20%
// faster: 2495 vs 2075 TF). Wave = 4 m-tiles x 2 n-tiles of 32x32; per phase
// 8 MFMA (one m-pair x one n-tile x 4 k-slices). Operands swapped (W as A-op)
// so D: lane&31 = token, reg=(reg&3)+8*(reg>>2)+4*(lane>>5) = out-col (m74/m101).
__global__ __launch_bounds__(512, 2) void grouped_gemm_256(
    const unsigned short* __restrict__ Abf,   // [T_TOK][D_INK] bf16
    const unsigned short* __restrict__ Wbf,   // [G][D_OUTN][D_INK] bf16
    const int* __restrict__ offs_raw,         // cumsum ends; int32 or int64-in-memory
    float* __restrict__ out)                  // [T_TOK][D_OUTN] fp32
{
    __shared__ unsigned short lds[2][32768];  // 2 dbuf x (A 32KB + B 32KB) = 128 KiB

    const int tid  = threadIdx.x;
    const int wave = tid >> 6;
    const int lane = tid & 63;

    // T1 variant (R6): XCD x owns an 8-mt band; co-resident sets = 4 nt x 8 mt.
    const int swz = (blockIdx.x & 7) * (MT_TILES * NT_TILES / 8) + (blockIdx.x >> 3);
    const int set = swz >> 5;
    const int idx = swz & 31;
    const int nt = (set & 7) * 4 + (idx & 3);
    const int mt = (set >> 3) * 8 + (idx >> 2);

    const int row0 = mt * BM;
    const int col0 = nt * BN;

    // group id (offsets int32, or int64 whose high words read as 0);
    // all group boundaries are multiples of 256 -> tiles never straddle.
    const int ostride = (offs_raw[1] == 0) ? 2 : 1;
    int g = 0;
#pragma unroll
    for (int i = 0; i < G_NUM - 1; ++i)
        if (row0 >= offs_raw[i * ostride]) g = i + 1;

    const unsigned short* Aorig = Abf + (size_t)row0 * D_INK;
    const unsigned short* Worig = Wbf + ((size_t)g * D_OUTN + col0) * D_INK;

    // staging lane geometry (unchanged): lane l covers subtile row l>>2,
    // cols ((l&3)*8) ^ ((l&32)?16:0) .. +8  (inverse st_16x32 swizzle on source)
    const int lrow = lane >> 2;
    const int gcol_off = ((lane & 3) * 8) ^ ((lane & 32) ? 16 : 0);

    // fragment-read lane geometry (mfma 32x32x16 bf16):
    // lane l holds row (l&31), k-bytes (l>>5)*16 .. +16 of a 32-row x K=16 slice.
    const int rl   = lane & 31;
    const int rlo  = rl & 15;                  // row within subtile
    const int rhi  = rl >> 4;                  // subtile-row step
    const int rxor = (rl & 8) ? 32 : 0;        // st_16x32 swizzle XOR
    const int klo  = (lane >> 5) * 16;         // k-byte base within 16-k slice
    const int wm16 = (wave >> 2) * 8;          // A subtile-row base (wave: 128 rows)
    const int wn16 = (wave & 3) * 4;           // B subtile-row base (wave: 64 rows)
    const int wm = (wave >> 2) * 128;
    const int wn = (wave & 3) * 64;

    char* ldsc = (char*)&lds[0][0];

    // stage one HALF-tile (128 rows x 64 k = 16 KB = 2 insts/thread) -- unchanged
    auto stageAh = [&](int buf, int kt, int h) {
#pragma unroll
        for (int i = 0; i < 2; ++i) {
            const int s = h * 16 + i * 8 + wave;
            const int sr = s >> 1, sc = s & 1;
            const unsigned short* src = Aorig + (size_t)(sr * 16 + lrow) * D_INK
                                        + kt * BK + sc * 32 + gcol_off;
            gload_lds16(src, ldsc + buf * 65536 + s * 1024);
        }
    };
    auto stageBh = [&](int buf, int kt, int h) {
#pragma unroll
        for (int i = 0; i < 2; ++i) {
            const int s = h * 16 + i * 8 + wave;
            const int sr = s >> 1, sc = s & 1;
            const unsigned short* src = Worig + (size_t)(sr * 16 + lrow) * D_INK
                                        + kt * BK + sc * 32 + gcol_off;
            gload_lds16(src, ldsc + buf * 65536 + 32768 + s * 1024);
        }
    };

    f32x16 acc[4][2] = {};      // [m-tile 32][n-tile 32], 16 f32 each = 128 VGPR
    bf16x8 w[2][4], x[2][4];    // [n-tile][k-slice], [m-of-pair][k-slice]

    // fragment read: subtile sidx = (subrow + rhi)*2 + (kb>>6);
    // intra = rlo*64 + ((kb&63) ^ rxor); kb = ks*32 + klo.
    auto ldW4 = [&](int buf, int ntl) {
#pragma unroll
        for (int ks = 0; ks < 4; ++ks) {
            const int kb = ks * 32 + klo;
            const int sidx = (wn16 + ntl * 2 + rhi) * 2 + (kb >> 6);
            w[ntl][ks] = *reinterpret_cast<const bf16x8*>(
                ldsc + buf * 65536 + 32768 + sidx * 1024 + rlo * 64 + ((kb & 63) ^ rxor));
        }
    };
    auto ldX8 = [&](int buf, int mtp) {
#pragma unroll
        for (int m = 0; m < 2; ++m)
#pragma unroll
            for (int ks = 0; ks < 4; ++ks) {
                const int kb = ks * 32 + klo;
                const int sidx = (wm16 + (mtp * 2 + m) * 2 + rhi) * 2 + (kb >> 6);
                x[m][ks] = *reinterpret_cast<const bf16x8*>(
                    ldsc + buf * 65536 + sidx * 1024 + rlo * 64 + ((kb & 63) ^ rxor));
            }
    };
    auto mmaq = [&](int mtp, int ntl) {
        __builtin_amdgcn_s_setprio(1);
#pragma unroll
        for (int ks = 0; ks < 4; ++ks)
#pragma unroll
            for (int m = 0; m < 2; ++m)
                acc[mtp * 2 + m][ntl] = __builtin_amdgcn_mfma_f32_32x32x16_bf16(
                    w[ntl][ks], x[m][ks], acc[mtp * 2 + m][ntl], 0, 0, 0);
        __builtin_amdgcn_s_setprio(0);
    };

    // prologue: tile0 (B then A) + B(1) = 12 insts; vmcnt(4) -> tile0 landed,
    // B(1) (4 insts) stays in flight == steady-state superstep entry condition.
    stageBh(0, 0, 0); stageBh(0, 0, 1);
    stageAh(0, 0, 0); stageAh(0, 0, 1);
    stageBh(1, 1, 0); stageBh(1, 1, 1);
    VMCNT(4);
    BARRIER();

    for (int t = 0; t < NKT; t += 2) {
        const bool s2 = (t + 2 < NKT), s3 = (t + 3 < NKT);

        // ---- tile t (buf0) ----
        // ph0: (m01 x n0); stage A(t+1) half0 -> buf1
        ldW4(0, 0); ldX8(0, 0);
        stageAh(1, t + 1, 0);
        BARRIER(); mmaq(0, 0); BARRIER();

        // ph1: (m01 x n1); stage A(t+1) half1
        ldW4(0, 1);
        stageAh(1, t + 1, 1);
        BARRIER(); mmaq(0, 1); BARRIER();

        // ph2: (m23 x n0); stage B(t+2) half0 -> buf0 (B[buf0] consumed at ph1)
        ldX8(0, 1);
        if (s2) stageBh(0, t + 2, 0);
        BARRIER(); mmaq(1, 0); BARRIER();

        // ph3: (m23 x n1), no ds-reads; stage B(t+2) half1;
        // vmcnt(4): waits B(t+1)+A(t+1) landed, leaves B(t+2) in flight.
        if (s2) stageBh(0, t + 2, 1);
        BARRIER();
        mmaq(1, 1);
        if (s2) { VMCNT(4); } else { VMCNT(0); }
        BARRIER();

        // ---- tile t+1 (buf1) ----
        // ph4: (m01 x n0); stage A(t+2) half0 -> buf0 (A[buf0] consumed at ph2)
        ldW4(1, 0); ldX8(1, 0);
        if (s2) stageAh(0, t + 2, 0);
        BARRIER(); mmaq(0, 0); BARRIER();

        // ph5: (m01 x n1); stage A(t+2) half1
        ldW4(1, 1);
        if (s2) stageAh(0, t + 2, 1);
        BARRIER(); mmaq(0, 1); BARRIER();

        // ph6: (m23 x n0); stage B(t+3) half0 -> buf1 (B[buf1] consumed at ph5)
        ldX8(1, 1);
        if (s3) stageBh(1, t + 3, 0);
        BARRIER(); mmaq(1, 0); BARRIER();

        // ph7: (m23 x n1); stage B(t+3) half1;
        // vmcnt(4): waits B(t+2)+A(t+2) landed, leaves B(t+3) in flight.
        if (s3) stageBh(1, t + 3, 1);
        BARRIER();
        mmaq(1, 1);
        if (s3) { VMCNT(4); } else { VMCNT(0); }
        BARRIER();
    }

    // ---- C-write (swapped 32x32 layout, m74/m101): lane&31 = token row,
    //      out-col = (reg&3) + 8*(reg>>2) + 4*(lane>>5) -> reg-quad = 4 contiguous
    //      cols -> one float4 store per (m-tile, n-tile, quad).
    const int tok_l = lane & 31;
    const int colq  = (lane >> 5) * 4;
#pragma unroll
    for (int mtl = 0; mtl < 4; ++mtl) {
        const size_t rbase = (size_t)(row0 + wm + mtl * 32 + tok_l) * D_OUTN;
#pragma unroll
        for (int ntl = 0; ntl < 2; ++ntl)
#pragma unroll
            for (int q = 0; q < 4; ++q) {
                f32x4 v = { acc[mtl][ntl][q * 4 + 0], acc[mtl][ntl][q * 4 + 1],
                            acc[mtl][ntl][q * 4 + 2], acc[mtl][ntl][q * 4 + 3] };
                *reinterpret_cast<f32x4*>(
                    &out[rbase + col0 + wn + ntl * 32 + colq + q * 8]) = v;
            }
    }
}

// ---------- fallback (only if d_ws too small): naive fp32 ----------
__global__ __launch_bounds__(256) void naive_grouped(
    const float* __restrict__ A, const float* __restrict__ W,
    const int* __restrict__ offs_raw, float* __restrict__ out)
{
    const long long total = (long long)T_TOK * D_OUTN;
    long long idx = (long long)blockIdx.x * blockDim.x + threadIdx.x;
    const long long stride = (long long)gridDim.x * blockDim.x;
    const int ostride = (offs_raw[1] == 0) ? 2 : 1;
    for (; idx < total; idx += stride) {
        const int t = (int)(idx / D_OUTN);
        const int c = (int)(idx % D_OUTN);
        int g = 0;
        for (int i = 0; i < G_NUM - 1; ++i)
            if (t >= offs_raw[i * ostride]) g = i + 1;
        const float4* a4 = reinterpret_cast<const float4*>(A + (size_t)t * D_INK);
        const float4* w4 = reinterpret_cast<const float4*>(W + ((size_t)g * D_OUTN + c) * D_INK);
        float s = 0.f;
        for (int k = 0; k < D_INK / 4; ++k) {
            float4 av = a4[k], wv = w4[k];
            s += av.x * wv.x + av.y * wv.y + av.z * wv.z + av.w * wv.w;
        }
        out[idx] = s;
    }
}

extern "C" void kernel_launch(void* const* d_in, const int* in_sizes, int n_in,
                              void* d_out, int out_size, void* d_ws, size_t ws_size,
                              hipStream_t stream) {
    const float* hidden = (const float*)d_in[0];
    const int*   offs   = (const int*)d_in[1];
    const float* weight = (const float*)d_in[2];
    float* out = (float*)d_out;

    const size_t nA = (size_t)T_TOK * D_INK;            // 33.5M
    const size_t nW = (size_t)G_NUM * D_OUTN * D_INK;   // 134M
    const size_t need = (nA + nW) * sizeof(unsigned short);

    if (ws_size >= need) {
        unsigned short* Abf = (unsigned short*)d_ws;
        unsigned short* Wbf = Abf + nA;
        cvt_f32_bf16<<<2048, 256, 0, stream>>>(hidden, Abf, (long long)(nA / 8));
        cvt_f32_bf16<<<4096, 256, 0, stream>>>(weight, Wbf, (long long)(nW / 8));
        grouped_gemm_256<<<MT_TILES * NT_TILES, 512, 0, stream>>>(Abf, Wbf, offs, out);
    } else {
        naive_grouped<<<8192, 256, 0, stream>>>(hidden, weight, offs, out);
    }
}

// Round 8
// 755.846 us; speedup vs baseline: 1.1082x; 1.1082x over previous
//
#include <hip/hip_runtime.h>
#include <stdint.h>

#define T_TOK   16384
#define D_INK   2048
#define D_OUTN  8192
#define G_NUM   8

#define BM 256
#define BN 256
#define BK 64
#define NKT (D_INK / BK)        // 32 K-tiles (even -> clean 2-tile supersteps)
#define MT_TILES (T_TOK / BM)   // 64
#define NT_TILES (D_OUTN / BN)  // 32
#define TILES_PER_BLK 8         // persistent: 256 blocks x 8 tiles = 2048

typedef __attribute__((ext_vector_type(8))) short bf16x8;
typedef __attribute__((ext_vector_type(4))) float f32x4;

#define BARRIER() do { asm volatile("" ::: "memory"); __builtin_amdgcn_s_barrier(); asm volatile("" ::: "memory"); } while (0)
#define VMCNT(n)  asm volatile("s_waitcnt vmcnt(" #n ")" ::: "memory")
#define CFENCE()  asm volatile("" ::: "memory")
// operand-swapped: D = W_frag x X_frag -> D.lane&15 = token row, reg-axis = output col
#define MFMA16(d,vw,vx) d = __builtin_amdgcn_mfma_f32_16x16x32_bf16(vw, vx, d, 0, 0, 0)

// ---------- fp32 -> bf16 (RNE) conversion, vectorized ----------
__device__ __forceinline__ unsigned int f2bf(float f) {
    union { float f; unsigned int u; } v; v.f = f;
    unsigned int u = v.u;
    unsigned int r = u + 0x7FFFu + ((u >> 16) & 1u);
    return r >> 16;
}

__global__ __launch_bounds__(256) void cvt_f32_bf16(const float* __restrict__ src,
                                                    unsigned short* __restrict__ dst,
                                                    long long n8) {
    long long i = (long long)blockIdx.x * blockDim.x + threadIdx.x;
    long long stride = (long long)gridDim.x * blockDim.x;
    const float4* s4 = reinterpret_cast<const float4*>(src);
    for (; i < n8; i += stride) {
        float4 x = s4[i * 2];
        float4 y = s4[i * 2 + 1];
        uint4 o;
        o.x = f2bf(x.x) | (f2bf(x.y) << 16);
        o.y = f2bf(x.z) | (f2bf(x.w) << 16);
        o.z = f2bf(y.x) | (f2bf(y.y) << 16);
        o.w = f2bf(y.z) | (f2bf(y.w) << 16);
        *reinterpret_cast<uint4*>(dst + i * 8) = o;
    }
}

// ---------- async global->LDS, 16B per lane ----------
__device__ __forceinline__ void gload_lds16(const unsigned short* g, void* l) {
    __builtin_amdgcn_global_load_lds(
        (const __attribute__((address_space(1))) void*)g,
        (__attribute__((address_space(3))) void*)l,
        16, 0, 0);
}

// ---------- persistent 256x256 8-phase grouped GEMM ----------
// Core = R4's best-measured structure (562 us, MfmaUtil 44%, bank conflicts 0):
// 16x16x32 MFMA, st_16x32-swizzled LDS (inverse swizzle folded into global src),
// 2-K-tile superstep, 8 phases, in-phase fragment reads (compiler counted-lgkm),
// one half-tile stage per phase, vmcnt(4) twice per superstep.
// NEW: persistent blocks (grid=256, 1/CU, 8 tiles each, same seq->tile mapping
// as the 2048-block version): next tile's 12 prologue loads issue BEFORE the
// epilogue stores, hiding HBM latency under store drain; vmcnt(36) (in-order
// retire) drains exactly the 8 oldest = next tile-0 loads.
__global__ __launch_bounds__(512, 2) void grouped_gemm_256(
    const unsigned short* __restrict__ Abf,   // [T_TOK][D_INK] bf16
    const unsigned short* __restrict__ Wbf,   // [G][D_OUTN][D_INK] bf16
    const int* __restrict__ offs_raw,         // cumsum ends; int32 or int64-in-memory
    float* __restrict__ out)                  // [T_TOK][D_OUTN] fp32
{
    __shared__ unsigned short lds[2][32768];  // 2 dbuf x (A 32KB + B 32KB) = 128 KiB

    const int tid  = threadIdx.x;
    const int wave = tid >> 6;
    const int lane = tid & 63;

    const int ostride = (offs_raw[1] == 0) ? 2 : 1;

    // staging lane geometry: lane l covers subtile row l>>2,
    // cols ((l&3)*8) ^ ((l&32)?16:0) .. +8  (inverse st_16x32 swizzle on source)
    const int lrow = lane >> 2;
    const int gcol_off = ((lane & 3) * 8) ^ ((lane & 32) ? 16 : 0);

    // fragment-read lane geometry (mfma 16x16x32 bf16)
    const int fr  = lane & 15;
    const int fk2 = (lane >> 4) << 4;
    const int swz_off = fr * 64 + (fk2 ^ ((fr & 8) ? 32 : 0));
    const int wm16 = (wave >> 2) * 8;          // A subtile-row base (wave: 128 rows)
    const int wn16 = (wave & 3) * 4;           // B subtile-row base (wave: 64 rows)
    const int wm = (wave >> 2) * 128;
    const int wn = (wave & 3) * 64;

    char* ldsc = (char*)&lds[0][0];

    // per-tile state (updated by setTile)
    int row0 = 0, col0 = 0;
    const unsigned short* Aorig = Abf;
    const unsigned short* Worig = Wbf;

    auto setTile = [&](int it) {
        const int seq = it * 256 + blockIdx.x;       // == original blockIdx order
        const int swz = (seq & 7) * (MT_TILES * NT_TILES / 8) + (seq >> 3);
        const int set = swz >> 5;
        const int idx = swz & 31;
        const int nt = (set & 7) * 4 + (idx & 3);
        const int mt = (set >> 3) * 8 + (idx >> 2);
        row0 = mt * BM;
        col0 = nt * BN;
        int g = 0;
#pragma unroll
        for (int i = 0; i < G_NUM - 1; ++i)
            if (row0 >= offs_raw[i * ostride]) g = i + 1;
        Aorig = Abf + (size_t)row0 * D_INK;
        Worig = Wbf + ((size_t)g * D_OUTN + col0) * D_INK;
    };

    // stage one HALF-tile (128 rows x 64 k = 16 KB = 2 insts/thread)
    auto stageAh = [&](int buf, int kt, int h) {
#pragma unroll
        for (int i = 0; i < 2; ++i) {
            const int s = h * 16 + i * 8 + wave;
            const int sr = s >> 1, sc = s & 1;
            const unsigned short* src = Aorig + (size_t)(sr * 16 + lrow) * D_INK
                                        + kt * BK + sc * 32 + gcol_off;
            gload_lds16(src, ldsc + buf * 65536 + s * 1024);
        }
    };
    auto stageBh = [&](int buf, int kt, int h) {
#pragma unroll
        for (int i = 0; i < 2; ++i) {
            const int s = h * 16 + i * 8 + wave;
            const int sr = s >> 1, sc = s & 1;
            const unsigned short* src = Worig + (size_t)(sr * 16 + lrow) * D_INK
                                        + kt * BK + sc * 32 + gcol_off;
            gload_lds16(src, ldsc + buf * 65536 + 32768 + s * 1024);
        }
    };
    auto prologue = [&]() {   // 12 loads: tile0 full (B then A) + B(1)
        stageBh(0, 0, 0); stageBh(0, 0, 1);
        stageAh(0, 0, 0); stageAh(0, 0, 1);
        stageBh(1, 1, 0); stageBh(1, 1, 1);
    };

    f32x4 acc[8][4] = {};
    bf16x8 a[4][2], b[4][2];

    auto ldB2 = [&](int buf, int jb) {
#pragma unroll
        for (int j = 0; j < 2; ++j) {
            const int sr = wn16 + jb + j;
            b[jb + j][0] = *reinterpret_cast<const bf16x8*>(ldsc + buf * 65536 + 32768 + (sr * 2 + 0) * 1024 + swz_off);
            b[jb + j][1] = *reinterpret_cast<const bf16x8*>(ldsc + buf * 65536 + 32768 + (sr * 2 + 1) * 1024 + swz_off);
        }
    };
    auto ldA4 = [&](int buf, int mb) {
#pragma unroll
        for (int i = 0; i < 4; ++i) {
            const int sr = wm16 + mb + i;
            a[i][0] = *reinterpret_cast<const bf16x8*>(ldsc + buf * 65536 + (sr * 2 + 0) * 1024 + swz_off);
            a[i][1] = *reinterpret_cast<const bf16x8*>(ldsc + buf * 65536 + (sr * 2 + 1) * 1024 + swz_off);
        }
    };
    auto quad = [&](int ib, int jb) {
        __builtin_amdgcn_s_setprio(1);
#pragma unroll
        for (int i = 0; i < 4; ++i)
#pragma unroll
            for (int j = 0; j < 2; ++j) {
                MFMA16(acc[ib + i][jb + j], b[jb + j][0], a[i][0]);
                MFMA16(acc[ib + i][jb + j], b[jb + j][1], a[i][1]);
            }
        __builtin_amdgcn_s_setprio(0);
    };

    // ---- initial prologue for tile 0
    setTile(0);
    prologue();
    VMCNT(4);          // tile0 landed; B(1) stays in flight
    BARRIER();

#pragma unroll 1
    for (int it = 0; it < TILES_PER_BLK; ++it) {

        // ================= K-loop (R4 schedule, verbatim) =================
        for (int t = 0; t < NKT; t += 2) {
            const bool s2 = (t + 2 < NKT), s3 = (t + 3 < NKT);

            // ---- tile t (buf0) ----
            ldB2(0, 0); ldA4(0, 0);
            stageAh(1, t + 1, 0);
            BARRIER(); quad(0, 0); BARRIER();

            ldB2(0, 2);
            stageAh(1, t + 1, 1);
            BARRIER(); quad(0, 2); BARRIER();

            ldA4(0, 4);
            if (s2) stageBh(0, t + 2, 0);
            BARRIER(); quad(4, 0); BARRIER();

            if (s2) stageBh(0, t + 2, 1);
            BARRIER();
            quad(4, 2);
            if (s2) { VMCNT(4); } else { VMCNT(0); }
            BARRIER();

            // ---- tile t+1 (buf1) ----
            ldB2(1, 0); ldA4(1, 0);
            if (s2) stageAh(0, t + 2, 0);
            BARRIER(); quad(0, 0); BARRIER();

            ldB2(1, 2);
            if (s2) stageAh(0, t + 2, 1);
            BARRIER(); quad(0, 2); BARRIER();

            ldA4(1, 4);
            if (s3) stageBh(1, t + 3, 0);
            BARRIER(); quad(4, 0); BARRIER();

            if (s3) stageBh(1, t + 3, 1);
            BARRIER();
            quad(4, 2);
            if (s3) { VMCNT(4); } else { VMCNT(0); }
            BARRIER();
        }
        // K-loop exits fully drained (vmcnt==0), all LDS reads done (final BARRIER).

        // save this tile's output coordinates before overwriting with next tile's
        const int srow0 = row0, scol0 = col0;

        // ---- issue NEXT tile's prologue BEFORE the epilogue stores ----
        if (it + 1 < TILES_PER_BLK) {
            setTile(it + 1);
            prologue();        // 12 loads into now-free LDS
            CFENCE();          // keep loads ahead of the stores below
        }

        // ---- epilogue (operand-swapped layout, verified R5): lane&15 = token
        //      row, (lane>>4)*4 + reg = output col -> one float4 store per (i,j).
        const int m_in   = lane & 15;
        const int n_base = (lane >> 4) * 4;
#pragma unroll
        for (int i = 0; i < 8; ++i) {
            const size_t rbase = (size_t)(srow0 + wm + i * 16 + m_in) * D_OUTN;
#pragma unroll
            for (int j = 0; j < 4; ++j) {
                const int cc = scol0 + wn + j * 16 + n_base;
                *reinterpret_cast<f32x4*>(&out[rbase + cc]) = acc[i][j];
            }
        }

        if (it + 1 < TILES_PER_BLK) {
            // zero accumulators for the next tile
#pragma unroll
            for (int i = 0; i < 8; ++i)
#pragma unroll
                for (int j = 0; j < 4; ++j)
#pragma unroll
                    for (int r = 0; r < 4; ++r) acc[i][j][r] = 0.0f;
            // in-order vmcnt retire: 12 loads issued before 32 stores; <=36
            // outstanding <=> 8 oldest (tile0's B+A) retired. B(1)+stores drain
            // under the first phases of the next K-loop (its ph3 vmcnt(4) covers).
            VMCNT(36);
            BARRIER();
        }
    }
}

// ---------- fallback (only if d_ws too small): naive fp32 ----------
__global__ __launch_bounds__(256) void naive_grouped(
    const float* __restrict__ A, const float* __restrict__ W,
    const int* __restrict__ offs_raw, float* __restrict__ out)
{
    const long long total = (long long)T_TOK * D_OUTN;
    long long idx = (long long)blockIdx.x * blockDim.x + threadIdx.x;
    const long long stride = (long long)gridDim.x * blockDim.x;
    const int ostride = (offs_raw[1] == 0) ? 2 : 1;
    for (; idx < total; idx += stride) {
        const int t = (int)(idx / D_OUTN);
        const int c = (int)(idx % D_OUTN);
        int g = 0;
        for (int i = 0; i < G_NUM - 1; ++i)
            if (t >= offs_raw[i * ostride]) g = i + 1;
        const float4* a4 = reinterpret_cast<const float4*>(A + (size_t)t * D_INK);
        const float4* w4 = reinterpret_cast<const float4*>(W + ((size_t)g * D_OUTN + c) * D_INK);
        float s = 0.f;
        for (int k = 0; k < D_INK / 4; ++k) {
            float4 av = a4[k], wv = w4[k];
            s += av.x * wv.x + av.y * wv.y + av.z * wv.z + av.w * wv.w;
        }
        out[idx] = s;
    }
}

extern "C" void kernel_launch(void* const* d_in, const int* in_sizes, int n_in,
                              void* d_out, int out_size, void* d_ws, size_t ws_size,
                              hipStream_t stream) {
    const float* hidden = (const float*)d_in[0];
    const int*   offs   = (const int*)d_in[1];
    const float* weight = (const float*)d_in[2];
    float* out = (float*)d_out;

    const size_t nA = (size_t)T_TOK * D_INK;            // 33.5M
    const size_t nW = (size_t)G_NUM * D_OUTN * D_INK;   // 134M
    const size_t need = (nA + nW) * sizeof(unsigned short);

    if (ws_size >= need) {
        unsigned short* Abf = (unsigned short*)d_ws;
        unsigned short* Wbf = Abf + nA;
        cvt_f32_bf16<<<2048, 256, 0, stream>>>(hidden, Abf, (long long)(nA / 8));
        cvt_f32_bf16<<<4096, 256, 0, stream>>>(weight, Wbf, (long long)(nW / 8));
        grouped_gemm_256<<<256, 512, 0, stream>>>(Abf, Wbf, offs, out);
    } else {
        naive_grouped<<<8192, 256, 0, stream>>>(hidden, weight, offs, out);
    }
}